// Round 5
// baseline (94.344 us; speedup 1.0000x reference)
//
#include <hip/hip_runtime.h>
#include <math.h>

namespace {

constexpr int kB = 8;
constexpr int kK = 4096;
constexpr int kC = 1024;
constexpr int kL = 32;            // chunk length along K
constexpr int kNC = kK / kL;      // 128 chunks per batch chain
constexpr int kNBLK = kB * kNC;   // 1024 blocks total
constexpr int kTPB = 256;         // 4 channels/thread covers C=1024

constexpr float kClamp = 1.0e4f;
constexpr float kMinD = 0.001f;
constexpr float kMaxD = 0.999f;
constexpr float kEps = 1e-6f;

typedef float f4 __attribute__((ext_vector_type(4)));

__device__ __forceinline__ float sanitize(float x) {
  x = (x != x) ? 0.0f : x;                       // NaN -> 0
  return fminf(kClamp, fmaxf(-kClamp, x));       // +-inf and clip -> +-1e4
}

__device__ __forceinline__ float softplusf(float x) {
  return fmaxf(x, 0.0f) + log1pf(expf(-fabsf(x)));
}

__device__ __forceinline__ float decay_of(float logit) {
  return kMinD + (kMaxD - kMinD) / (1.0f + expf(-logit));
}

union f2u {
  unsigned long long u;
  float f[2];
};

// Zero per-chunk flags each call (harness does not re-poison d_ws between
// timed replays, and poisons 0xAA once before timing).
__global__ void k_init(int* __restrict__ flags) {
  const int i = blockIdx.x * blockDim.x + threadIdx.x;
  if (i < kNBLK) flags[i] = 0;
}

// Single-pass chunked scan with decoupled lookback.
// Cross-block data (carries + flags) moves via relaxed AGENT-scope atomics
// (sc1: bypass per-XCD L2, talk to the coherence point). NO __threadfence():
// an agent acquire fence would buffer_inv the whole per-XCD L2 and destroy
// Phase B's token cache hits (R2 regression, fixed in R4).
// Lookback waits are PARALLEL: thread t spins on flag[t] (R4's thread-0
// serial walk cost ~63 dependent L3 round-trips ~= 16 us for late blocks).
__global__ __launch_bounds__(kTPB) void k_scan(
    const float* __restrict__ tokens, const float* __restrict__ state,
    const float* __restrict__ dlog, const float* __restrict__ igr,
    const float* __restrict__ ogr, const float* __restrict__ sbias,
    float* __restrict__ out, float* __restrict__ final_out,
    unsigned long long* __restrict__ carry, int* __restrict__ flags) {
  const int gid = blockIdx.x;
  const int b = gid / kNC;
  const int j = gid - b * kNC;
  const int c0 = threadIdx.x * 4;

  // --- per-channel constrained parameters (4 channels/thread) ---
  const f4 dl = *reinterpret_cast<const f4*>(dlog + c0);
  const f4 ig = *reinterpret_cast<const f4*>(igr + c0);
  const f4 og = *reinterpret_cast<const f4*>(ogr + c0);
  const f4 sb = *reinterpret_cast<const f4*>(sbias + c0);

  const float d0 = decay_of(dl.x), d1 = decay_of(dl.y);
  const float d2 = decay_of(dl.z), d3 = decay_of(dl.w);
  const float g0 = softplusf(ig.x) + kEps, g1 = softplusf(ig.y) + kEps;
  const float g2 = softplusf(ig.z) + kEps, g3 = softplusf(ig.w) + kEps;
  // b_t = (1-d)*(g*x + bias) = a*x + bb
  const float a0 = (1.0f - d0) * g0, a1 = (1.0f - d1) * g1;
  const float a2 = (1.0f - d2) * g2, a3 = (1.0f - d3) * g3;
  const float bb0 = (1.0f - d0) * sb.x, bb1 = (1.0f - d1) * sb.y;
  const float bb2 = (1.0f - d2) * sb.z, bb3 = (1.0f - d3) * sb.w;
  const float o0 = softplusf(og.x) + kEps, o1 = softplusf(og.y) + kEps;
  const float o2 = softplusf(og.z) + kEps, o3 = softplusf(og.w) + kEps;

  const float* tp = tokens + (((size_t)b * kK) + (size_t)j * kL) * kC + c0;

  // --- Phase A: zero-init local scan -> chunk carry (warms L2/L3) ---
  float s0 = 0.0f, s1 = 0.0f, s2 = 0.0f, s3 = 0.0f;
  for (int i = 0; i < kL; i += 8) {
    f4 x[8];
#pragma unroll
    for (int u = 0; u < 8; ++u)
      x[u] = *reinterpret_cast<const f4*>(tp + (size_t)(i + u) * kC);
#pragma unroll
    for (int u = 0; u < 8; ++u) {
      s0 = fmaf(d0, s0, fmaf(a0, sanitize(x[u].x), bb0));
      s1 = fmaf(d1, s1, fmaf(a1, sanitize(x[u].y), bb1));
      s2 = fmaf(d2, s2, fmaf(a2, sanitize(x[u].z), bb2));
      s3 = fmaf(d3, s3, fmaf(a3, sanitize(x[u].w), bb3));
    }
  }
  // Publish carry to the coherence point (sc1 stores, no fence needed).
  {
    const size_t ci = ((size_t)gid * kC + c0) / 2;  // ULL index
    f2u lo, hi;
    lo.f[0] = s0; lo.f[1] = s1; hi.f[0] = s2; hi.f[1] = s3;
    __hip_atomic_store(carry + ci, lo.u, __ATOMIC_RELAXED,
                       __HIP_MEMORY_SCOPE_AGENT);
    __hip_atomic_store(carry + ci + 1, hi.u, __ATOMIC_RELAXED,
                       __HIP_MEMORY_SCOPE_AGENT);
  }
  // Barrier drains vmcnt for ALL threads' carry stores, then thread 0
  // releases the flag (relaxed is enough: data already at coherence point).
  __syncthreads();
  if (threadIdx.x == 0) {
    __hip_atomic_store(flags + gid, 1, __ATOMIC_RELAXED,
                       __HIP_MEMORY_SCOPE_AGENT);
  }

  // --- Lookback: parallel wait for all predecessors in this chain ---
  // j <= 127 < 256 threads: thread t waits on predecessor t's flag.
  const int base = b * kNC;
  if (threadIdx.x < j) {
    while (__hip_atomic_load(flags + base + threadIdx.x, __ATOMIC_RELAXED,
                             __HIP_MEMORY_SCOPE_AGENT) == 0) {
      __builtin_amdgcn_s_sleep(2);
    }
  }
  __syncthreads();  // workgroup barrier only — no L2 invalidate

  // d^L per channel (L=32 -> 5 squarings)
  float dL0 = d0, dL1 = d1, dL2 = d2, dL3 = d3;
#pragma unroll
  for (int i = 0; i < 5; ++i) {
    dL0 *= dL0; dL1 *= dL1; dL2 *= dL2; dL3 *= dL3;
  }

  // Deterministic forward Horner over predecessor aggregates.
  const f4 st = *reinterpret_cast<const f4*>(state + (size_t)b * kC + c0);
  float S0 = st.x, S1 = st.y, S2 = st.z, S3 = st.w;
#pragma unroll 4
  for (int p = 0; p < j; ++p) {
    const size_t ci = ((size_t)(base + p) * kC + c0) / 2;
    f2u lo, hi;
    lo.u = __hip_atomic_load(carry + ci, __ATOMIC_RELAXED,
                             __HIP_MEMORY_SCOPE_AGENT);
    hi.u = __hip_atomic_load(carry + ci + 1, __ATOMIC_RELAXED,
                             __HIP_MEMORY_SCOPE_AGENT);
    S0 = fmaf(dL0, S0, lo.f[0]);
    S1 = fmaf(dL1, S1, lo.f[1]);
    S2 = fmaf(dL2, S2, hi.f[0]);
    S3 = fmaf(dL3, S3, hi.f[1]);
  }

  // --- Phase B: re-scan chunk from true start state, write outputs ---
  float* op = out + (((size_t)b * kK) + (size_t)j * kL) * kC + c0;
  s0 = S0; s1 = S1; s2 = S2; s3 = S3;
  for (int i = 0; i < kL; i += 8) {
    f4 x[8];
#pragma unroll
    for (int u = 0; u < 8; ++u)
      x[u] = *reinterpret_cast<const f4*>(tp + (size_t)(i + u) * kC);
#pragma unroll
    for (int u = 0; u < 8; ++u) {
      s0 = fmaf(d0, s0, fmaf(a0, sanitize(x[u].x), bb0));
      s1 = fmaf(d1, s1, fmaf(a1, sanitize(x[u].y), bb1));
      s2 = fmaf(d2, s2, fmaf(a2, sanitize(x[u].z), bb2));
      s3 = fmaf(d3, s3, fmaf(a3, sanitize(x[u].w), bb3));
      f4 y; y.x = o0 * s0; y.y = o1 * s1; y.z = o2 * s2; y.w = o3 * s3;
      *reinterpret_cast<f4*>(op + (size_t)(i + u) * kC) = y;
    }
  }

  if (j == kNC - 1) {
    f4 fv; fv.x = s0; fv.y = s1; fv.z = s2; fv.w = s3;
    *reinterpret_cast<f4*>(final_out + (size_t)b * kC + c0) = fv;
  }
}

}  // namespace

extern "C" void kernel_launch(void* const* d_in, const int* in_sizes, int n_in,
                              void* d_out, int out_size, void* d_ws, size_t ws_size,
                              hipStream_t stream) {
  const float* tokens = (const float*)d_in[0];
  const float* state  = (const float*)d_in[1];
  const float* dlog   = (const float*)d_in[2];
  const float* igr    = (const float*)d_in[3];
  const float* ogr    = (const float*)d_in[4];
  const float* sbias  = (const float*)d_in[5];

  float* out = (float*)d_out;                     // [B,K,C] outputs
  float* final_out = out + (size_t)kB * kK * kC;  // [B,C] final state

  unsigned long long* carry = (unsigned long long*)d_ws;  // kNBLK*kC floats (4 MiB)
  int* flags = (int*)((char*)d_ws + (size_t)kNBLK * kC * sizeof(float));

  k_init<<<dim3((kNBLK + 255) / 256), 256, 0, stream>>>(flags);
  k_scan<<<dim3(kNBLK), kTPB, 0, stream>>>(tokens, state, dlog, igr, ogr,
                                           sbias, out, final_out, carry, flags);
}

// Round 6
// 76.758 us; speedup vs baseline: 1.2291x; 1.2291x over previous
//
#include <hip/hip_runtime.h>
#include <math.h>

namespace {

constexpr int kB = 8;
constexpr int kK = 4096;
constexpr int kC = 1024;
constexpr int kL = 64;            // chunk length along K
constexpr int kNC = kK / kL;      // 64 chunks per batch chain
constexpr int kNBLK = kB * kNC;   // 512 blocks total
constexpr int kTPB = 256;         // 4 channels/thread covers C=1024

constexpr float kClamp = 1.0e4f;
constexpr float kMinD = 0.001f;
constexpr float kMaxD = 0.999f;
constexpr float kEps = 1e-6f;

typedef float f4 __attribute__((ext_vector_type(4)));

__device__ __forceinline__ float sanitize(float x) {
  x = (x != x) ? 0.0f : x;                       // NaN -> 0
  return fminf(kClamp, fmaxf(-kClamp, x));       // +-inf and clip -> +-1e4
}

__device__ __forceinline__ float softplusf(float x) {
  return fmaxf(x, 0.0f) + log1pf(expf(-fabsf(x)));
}

__device__ __forceinline__ float decay_of(float logit) {
  return kMinD + (kMaxD - kMinD) / (1.0f + expf(-logit));
}

union f2u {
  unsigned long long u;
  float f[2];
};

// Zero per-chunk flags each call (harness does not re-poison d_ws between
// timed replays, and poisons 0xAA once before timing).
__global__ void k_init(int* __restrict__ flags) {
  const int i = blockIdx.x * blockDim.x + threadIdx.x;
  if (i < kNBLK) flags[i] = 0;
}

// Single-pass chunked scan with decoupled lookback.
// - Cross-block data (carries + flags) via relaxed AGENT-scope atomics
//   (sc1: bypass per-XCD L2, talk to the coherence point). NO __threadfence:
//   an agent acquire fence buffer_inv's the whole per-XCD L2 and destroys
//   Phase B's token cache hits (R2 regression: 152 us).
// - kL=64: Horner carry traffic is quadratic in chunk count; kL=32 (R5)
//   quadrupled it and regressed (94 us).
// - Parallel flag wait: thread t spins on flag t; R4's thread-0 serial walk
//   was ~63 dependent coherence-latency loads (~16 us) for late blocks.
__global__ __launch_bounds__(kTPB) void k_scan(
    const float* __restrict__ tokens, const float* __restrict__ state,
    const float* __restrict__ dlog, const float* __restrict__ igr,
    const float* __restrict__ ogr, const float* __restrict__ sbias,
    float* __restrict__ out, float* __restrict__ final_out,
    unsigned long long* __restrict__ carry, int* __restrict__ flags) {
  const int gid = blockIdx.x;
  const int b = gid / kNC;
  const int j = gid - b * kNC;
  const int c0 = threadIdx.x * 4;

  // --- per-channel constrained parameters (4 channels/thread) ---
  const f4 dl = *reinterpret_cast<const f4*>(dlog + c0);
  const f4 ig = *reinterpret_cast<const f4*>(igr + c0);
  const f4 og = *reinterpret_cast<const f4*>(ogr + c0);
  const f4 sb = *reinterpret_cast<const f4*>(sbias + c0);

  const float d0 = decay_of(dl.x), d1 = decay_of(dl.y);
  const float d2 = decay_of(dl.z), d3 = decay_of(dl.w);
  const float g0 = softplusf(ig.x) + kEps, g1 = softplusf(ig.y) + kEps;
  const float g2 = softplusf(ig.z) + kEps, g3 = softplusf(ig.w) + kEps;
  // b_t = (1-d)*(g*x + bias) = a*x + bb
  const float a0 = (1.0f - d0) * g0, a1 = (1.0f - d1) * g1;
  const float a2 = (1.0f - d2) * g2, a3 = (1.0f - d3) * g3;
  const float bb0 = (1.0f - d0) * sb.x, bb1 = (1.0f - d1) * sb.y;
  const float bb2 = (1.0f - d2) * sb.z, bb3 = (1.0f - d3) * sb.w;
  const float o0 = softplusf(og.x) + kEps, o1 = softplusf(og.y) + kEps;
  const float o2 = softplusf(og.z) + kEps, o3 = softplusf(og.w) + kEps;

  const float* tp = tokens + (((size_t)b * kK) + (size_t)j * kL) * kC + c0;

  // --- Phase A: zero-init local scan -> chunk carry (warms L2/L3) ---
  float s0 = 0.0f, s1 = 0.0f, s2 = 0.0f, s3 = 0.0f;
  for (int i = 0; i < kL; i += 8) {
    f4 x[8];
#pragma unroll
    for (int u = 0; u < 8; ++u)
      x[u] = *reinterpret_cast<const f4*>(tp + (size_t)(i + u) * kC);
#pragma unroll
    for (int u = 0; u < 8; ++u) {
      s0 = fmaf(d0, s0, fmaf(a0, sanitize(x[u].x), bb0));
      s1 = fmaf(d1, s1, fmaf(a1, sanitize(x[u].y), bb1));
      s2 = fmaf(d2, s2, fmaf(a2, sanitize(x[u].z), bb2));
      s3 = fmaf(d3, s3, fmaf(a3, sanitize(x[u].w), bb3));
    }
  }
  // Publish carry to the coherence point (sc1 stores, no fence needed).
  {
    const size_t ci = ((size_t)gid * kC + c0) / 2;  // ULL index
    f2u lo, hi;
    lo.f[0] = s0; lo.f[1] = s1; hi.f[0] = s2; hi.f[1] = s3;
    __hip_atomic_store(carry + ci, lo.u, __ATOMIC_RELAXED,
                       __HIP_MEMORY_SCOPE_AGENT);
    __hip_atomic_store(carry + ci + 1, hi.u, __ATOMIC_RELAXED,
                       __HIP_MEMORY_SCOPE_AGENT);
  }
  // Barrier drains vmcnt for ALL threads' carry stores, then thread 0
  // releases the flag (relaxed is enough: data already at coherence point).
  __syncthreads();
  if (threadIdx.x == 0) {
    __hip_atomic_store(flags + gid, 1, __ATOMIC_RELAXED,
                       __HIP_MEMORY_SCOPE_AGENT);
  }

  // --- Lookback: PARALLEL wait for all predecessors in this chain ---
  // j <= 63 < 256 threads: thread t waits on predecessor t's flag.
  const int base = b * kNC;
  if (threadIdx.x < j) {
    while (__hip_atomic_load(flags + base + threadIdx.x, __ATOMIC_RELAXED,
                             __HIP_MEMORY_SCOPE_AGENT) == 0) {
      __builtin_amdgcn_s_sleep(2);
    }
  }
  __syncthreads();  // workgroup barrier only — no L2 invalidate

  // d^L per channel (L=64 -> 6 squarings)
  float dL0 = d0, dL1 = d1, dL2 = d2, dL3 = d3;
#pragma unroll
  for (int i = 0; i < 6; ++i) {
    dL0 *= dL0; dL1 *= dL1; dL2 *= dL2; dL3 *= dL3;
  }

  // Deterministic forward Horner over predecessor aggregates.
  const f4 st = *reinterpret_cast<const f4*>(state + (size_t)b * kC + c0);
  float S0 = st.x, S1 = st.y, S2 = st.z, S3 = st.w;
#pragma unroll 8
  for (int p = 0; p < j; ++p) {
    const size_t ci = ((size_t)(base + p) * kC + c0) / 2;
    f2u lo, hi;
    lo.u = __hip_atomic_load(carry + ci, __ATOMIC_RELAXED,
                             __HIP_MEMORY_SCOPE_AGENT);
    hi.u = __hip_atomic_load(carry + ci + 1, __ATOMIC_RELAXED,
                             __HIP_MEMORY_SCOPE_AGENT);
    S0 = fmaf(dL0, S0, lo.f[0]);
    S1 = fmaf(dL1, S1, lo.f[1]);
    S2 = fmaf(dL2, S2, hi.f[0]);
    S3 = fmaf(dL3, S3, hi.f[1]);
  }

  // --- Phase B: re-scan chunk from true start state, write outputs ---
  float* op = out + (((size_t)b * kK) + (size_t)j * kL) * kC + c0;
  s0 = S0; s1 = S1; s2 = S2; s3 = S3;
  for (int i = 0; i < kL; i += 8) {
    f4 x[8];
#pragma unroll
    for (int u = 0; u < 8; ++u)
      x[u] = *reinterpret_cast<const f4*>(tp + (size_t)(i + u) * kC);
#pragma unroll
    for (int u = 0; u < 8; ++u) {
      s0 = fmaf(d0, s0, fmaf(a0, sanitize(x[u].x), bb0));
      s1 = fmaf(d1, s1, fmaf(a1, sanitize(x[u].y), bb1));
      s2 = fmaf(d2, s2, fmaf(a2, sanitize(x[u].z), bb2));
      s3 = fmaf(d3, s3, fmaf(a3, sanitize(x[u].w), bb3));
      f4 y; y.x = o0 * s0; y.y = o1 * s1; y.z = o2 * s2; y.w = o3 * s3;
      *reinterpret_cast<f4*>(op + (size_t)(i + u) * kC) = y;
    }
  }

  if (j == kNC - 1) {
    f4 fv; fv.x = s0; fv.y = s1; fv.z = s2; fv.w = s3;
    *reinterpret_cast<f4*>(final_out + (size_t)b * kC + c0) = fv;
  }
}

}  // namespace

extern "C" void kernel_launch(void* const* d_in, const int* in_sizes, int n_in,
                              void* d_out, int out_size, void* d_ws, size_t ws_size,
                              hipStream_t stream) {
  const float* tokens = (const float*)d_in[0];
  const float* state  = (const float*)d_in[1];
  const float* dlog   = (const float*)d_in[2];
  const float* igr    = (const float*)d_in[3];
  const float* ogr    = (const float*)d_in[4];
  const float* sbias  = (const float*)d_in[5];

  float* out = (float*)d_out;                     // [B,K,C] outputs
  float* final_out = out + (size_t)kB * kK * kC;  // [B,C] final state

  unsigned long long* carry = (unsigned long long*)d_ws;  // kNBLK*kC floats (2 MiB)
  int* flags = (int*)((char*)d_ws + (size_t)kNBLK * kC * sizeof(float));

  k_init<<<dim3((kNBLK + 255) / 256), 256, 0, stream>>>(flags);
  k_scan<<<dim3(kNBLK), kTPB, 0, stream>>>(tokens, state, dlog, igr, ogr,
                                           sbias, out, final_out, carry, flags);
}